// Round 1
// 277.692 us; speedup vs baseline: 1.0147x; 1.0147x over previous
//
#include <hip/hip_runtime.h>

#define NUM_USERS 50000
#define NUM_ITEMS 50000
#define N_NODES   100000
#define NNZ       3200000
#define EMB_DIM   64
#define N_LAYERS  3
#define BATCH     16384

#define NBUCK 512
#define ABITS 8                  // bucket = dst >> 8 (256 nodes/bucket, 391 used)
#define NODES_PER_BUCK 256
#define TILE_EDGES 8192
#define NBUCK_USED ((N_NODES + NODES_PER_BUCK - 1) / NODES_PER_BUCK)   // 391
#define CAP 9216                 // padded bucket capacity (mean 8192; node-pad avg +384 -> ~7 sigma slack)

typedef unsigned long long ull;
typedef float v2f __attribute__((ext_vector_type(2)));

// ---- bf16 helpers (RNE) ----
__device__ inline unsigned bf16pair(float a, float b) {
    unsigned ua = __float_as_uint(a), ub = __float_as_uint(b);
    unsigned r0 = (ua + 0x7fffu + ((ua >> 16) & 1u)) >> 16;
    unsigned r1 = (ub + 0x7fffu + ((ub >> 16) & 1u)) >> 16;
    return r0 | (r1 << 16);
}
__device__ inline float blo(unsigned u) { return __uint_as_float(u << 16); }
__device__ inline float bhi(unsigned u) { return __uint_as_float(u & 0xffff0000u); }

// packed 2xf32 FMA: d = a*b + d  (VOP3P v_pk_fma_f32, halves independent)
__device__ inline void pkfma(v2f& d, v2f a, v2f b) {
    asm("v_pk_fma_f32 %0, %1, %2, %0" : "+v"(d) : "v"(a), "v"(b));
}

// accumulate one edge's 8 bf16 dims (uint4) with UNscaled integer weight (r>>17).
// 2^-15 scale folded into epilogue (exact power of 2 -> bit-identical weights).
__device__ inline void accP(v2f& sA, v2f& sB, v2f& sC, v2f& sD, uint4 g, unsigned r) {
    float w = (float)(r >> 17);
    v2f w2 = {w, w};
    v2f e0 = {blo(g.x), bhi(g.x)};
    v2f e1 = {blo(g.y), bhi(g.y)};
    v2f e2 = {blo(g.z), bhi(g.z)};
    v2f e3 = {blo(g.w), bhi(g.w)};
    pkfma(sA, e0, w2);
    pkfma(sB, e1, w2);
    pkfma(sC, e2, w2);
    pkfma(sD, e3, w2);
}

// gather one uint4 (8 bf16 dims) of node src at dim-octet byte offset dOff.
// 32-bit offset math + uniform base -> SADDR global_load (fewer VALU ops).
__device__ inline uint4 gath(const unsigned char* __restrict__ base, unsigned r, unsigned dOff) {
    unsigned off = ((r & 0x1FFFFu) << 7) + dOff;
    return *(const uint4*)(base + off);
}

// init: E0(bf16) = concat(ue, ie). Block 0 inits bucket cursors.
// Fused flag pass: flags[n]=1 for batch nodes (no zeroing: poison 0xAA != 1;
// spurious stale 1 only costs harmless extra compute in the gated pull).
__global__ void init_emb_kernel(const float* __restrict__ ue,
                                const float* __restrict__ ie,
                                unsigned* __restrict__ E0,
                                int* __restrict__ bucketCursor,
                                unsigned char* __restrict__ flags,
                                const int* __restrict__ users,
                                const int* __restrict__ items) {
    int idx = blockIdx.x * blockDim.x + threadIdx.x;   // per float4 (4 dims)
    if (blockIdx.x == 0 && threadIdx.x < 256) {
        bucketCursor[threadIdx.x]       = threadIdx.x * CAP;
        bucketCursor[threadIdx.x + 256] = (threadIdx.x + 256) * CAP;
    }
    if (idx < BATCH) {
        flags[users[idx]] = 1;
    } else if (idx < 2 * BATCH) {
        flags[NUM_USERS + items[idx - BATCH]] = 1;
    }
    const int total = N_NODES * (EMB_DIM / 4);
    if (idx >= total) return;
    const int uoff = NUM_USERS * (EMB_DIM / 4);
    float4 v;
    if (idx < uoff) v = ((const float4*)ue)[idx];
    else            v = ((const float4*)ie)[idx - uoff];
    uint2 h;
    h.x = bf16pair(v.x, v.y);
    h.y = bf16pair(v.z, v.w);
    ((uint2*)E0)[idx] = h;
}

// partition edges into padded dst-bucket regions. 1024 threads, 8 edges/thread.
// rec: src(17) | dstLocal(8)<<17 | fix15(val)<<25
__global__ void partA_kernel(const float* __restrict__ ev,
                             const int*  __restrict__ es,
                             const int*  __restrict__ ed,
                             int* __restrict__ bucketCursor,
                             ull* __restrict__ tmp) {
    __shared__ int hist[NBUCK];
    __shared__ int base[NBUCK];
    __shared__ int cnt2[NBUCK];
    int tid = threadIdx.x;            // 1024
    int e0 = blockIdx.x * TILE_EDGES;

    int      mySrc[8], myDst[8];
    unsigned myQ[8];

    for (int i = tid; i < NBUCK; i += 1024) hist[i] = 0;
    __syncthreads();

    #pragma unroll
    for (int k = 0; k < 8; ++k) {
        int e = e0 + k * 1024 + tid;
        if (e < NNZ) {
            mySrc[k] = es[e];
            myDst[k] = ed[e];
            myQ[k]   = (unsigned)fminf(ev[e] * 32768.f + 0.5f, 32767.f);
            atomicAdd(&hist[((unsigned)myDst[k]) >> ABITS], 1);
        } else {
            myDst[k] = -1;
        }
    }
    __syncthreads();

    for (int i = tid; i < NBUCK; i += 1024) {
        int c = hist[i];
        base[i] = c ? atomicAdd(&bucketCursor[i], c) : 0;
        cnt2[i] = 0;
    }
    __syncthreads();

    #pragma unroll
    for (int k = 0; k < 8; ++k) {
        int dst = myDst[k];
        if (dst < 0) continue;
        int b = ((unsigned)dst) >> ABITS;
        int pos = base[b] + atomicAdd(&cnt2[b], 1);
        if (pos < (b + 1) * CAP) {   // statistically unreachable overflow guard
            ull rec = (ull)(unsigned)(mySrc[k] | ((dst & (NODES_PER_BUCK - 1)) << 17))
                    | ((ull)myQ[k] << 25);
            tmp[pos] = rec;
        }
    }
}

// partB: per bucket — register-cache records (<=9/thread), degrees + rowStart via
// LDS scan, scatter to padded-CSR positions. Each node's segment start is padded
// to a multiple of 4 records (16 B) so pull can use dwordx4/dwordx2 record loads.
// Pad slots are never read (pull reads < deg only). sorted rec (u32): src(17)|fix15<<17
__global__ void partB_kernel(const ull* __restrict__ tmp,
                             const int* __restrict__ bucketCursor,
                             int* __restrict__ rowStart,
                             int* __restrict__ deg,
                             unsigned* __restrict__ sorted) {
    __shared__ int cnt[NODES_PER_BUCK];
    __shared__ int sc[NODES_PER_BUCK];
    __shared__ int cur[NODES_PER_BUCK];
    int b = blockIdx.x;
    int tid = threadIdx.x;           // 1024
    int nodeLo = b << ABITS;
    int startE = b * CAP;
    int endE   = bucketCursor[b];    // base + edges in bucket

    if (tid < NODES_PER_BUCK) cnt[tid] = 0;
    __syncthreads();

    ull myRec[9];
    int nRec = 0;
    #pragma unroll
    for (int k = 0; k < 9; ++k) {
        int i = startE + k * 1024 + tid;
        if (i < endE) {
            myRec[k] = tmp[i];
            nRec = k + 1;
            atomicAdd(&cnt[(int)((myRec[k] >> 17) & (NODES_PER_BUCK - 1))], 1);
        }
    }
    __syncthreads();

    if (tid < NODES_PER_BUCK) sc[tid] = (cnt[tid] + 3) & ~3;   // pad node seg to 4 recs
    __syncthreads();
    for (int o = 1; o < NODES_PER_BUCK; o <<= 1) {
        int add = 0;
        if (tid < NODES_PER_BUCK && tid >= o) add = sc[tid - o];
        __syncthreads();
        if (tid < NODES_PER_BUCK) sc[tid] += add;
        __syncthreads();
    }
    if (tid < NODES_PER_BUCK) {
        int node = nodeLo + tid;
        int pc = (cnt[tid] + 3) & ~3;
        int rs = startE + sc[tid] - pc;          // 16B-aligned (startE%4==0, scan of x4)
        cur[tid] = rs;
        if (node < N_NODES) {
            rowStart[node] = rs;
            deg[node] = cnt[tid];
        }
    }
    __syncthreads();

    for (int k = 0; k < nRec; ++k) {
        ull rec = myRec[k];
        int dl = (int)((rec >> 17) & (NODES_PER_BUCK - 1));
        unsigned o = (unsigned)(rec & 0x1FFFFULL) | ((unsigned)((rec >> 25) & 0x7FFF) << 17);
        int pos = atomicAdd(&cur[dl], 1);
        if (pos < startE + CAP) sorted[pos] = o;  // pad-overflow guard (stat. unreachable)
    }
}

// ---- pull: one wave per dst node; lane = (eg=lane>>3, d8=lane&7).
// dwordx4 record loads (lane owns 4 consecutive records), SADDR 32-bit gathers,
// v_pk_fma_f32 accumulation, weight scale folded into epilogue.
// Tail = optional 16-block + one predicated 16-wide round (r=0 -> w=0).
__global__ void pull_kernel(const unsigned char* __restrict__ A16,
                            uint4* __restrict__ B16,
                            const unsigned* __restrict__ sorted,
                            const int* __restrict__ rowStart,
                            const int* __restrict__ deg,
                            const unsigned char* __restrict__ flags,
                            int gate) {
    int node = __builtin_amdgcn_readfirstlane((blockIdx.x << 2) + (threadIdx.x >> 6));
    if (node >= N_NODES) return;
    if (gate && flags[node] != 1) return;   // wave-uniform
    int lane = threadIdx.x & 63;
    int eg = lane >> 3;                 // 0..7: edge group
    unsigned dOff = (unsigned)(lane & 7) << 4;   // dim octet byte offset
    int start = rowStart[node];         // scalar (node is SGPR)
    int cnt   = deg[node];
    const unsigned* ep = sorted + start;     // 16B-aligned (partB padding)

    v2f sA = {0.f, 0.f}, sB = {0.f, 0.f}, sC = {0.f, 0.f}, sD = {0.f, 0.f};
    int j = 0;
    while (j + 32 <= cnt) {
        uint4 R = *(const uint4*)(ep + j + (eg << 2));   // edges j+4eg .. j+4eg+3
        uint4 g0 = gath(A16, R.x, dOff);
        uint4 g1 = gath(A16, R.y, dOff);
        uint4 g2 = gath(A16, R.z, dOff);
        uint4 g3 = gath(A16, R.w, dOff);
        accP(sA, sB, sC, sD, g0, R.x);
        accP(sA, sB, sC, sD, g1, R.y);
        accP(sA, sB, sC, sD, g2, R.z);
        accP(sA, sB, sC, sD, g3, R.w);
        j += 32;
    }
    int rem = cnt - j;                  // 0..31
    if (rem >= 16) {
        uint2 R = *(const uint2*)(ep + j + (eg << 1));   // edges j+2eg, j+2eg+1
        uint4 g0 = gath(A16, R.x, dOff);
        uint4 g1 = gath(A16, R.y, dOff);
        accP(sA, sB, sC, sD, g0, R.x);
        accP(sA, sB, sC, sD, g1, R.y);
        j += 16; rem -= 16;
    }
    if (rem > 0) {                      // 1..15 edges, one predicated round
        int i0 = j + eg, i1 = j + 8 + eg;
        unsigned r0 = (i0 < cnt) ? ep[i0] : 0u;   // r=0 -> w=0, gather hits line 0
        unsigned r1 = (i1 < cnt) ? ep[i1] : 0u;
        uint4 g0 = gath(A16, r0, dOff);
        uint4 g1 = gath(A16, r1, dOff);
        accP(sA, sB, sC, sD, g0, r0);
        accP(sA, sB, sC, sD, g1, r1);
    }

    sA.x += __shfl_xor(sA.x, 8, 64);  sA.y += __shfl_xor(sA.y, 8, 64);
    sB.x += __shfl_xor(sB.x, 8, 64);  sB.y += __shfl_xor(sB.y, 8, 64);
    sC.x += __shfl_xor(sC.x, 8, 64);  sC.y += __shfl_xor(sC.y, 8, 64);
    sD.x += __shfl_xor(sD.x, 8, 64);  sD.y += __shfl_xor(sD.y, 8, 64);
    sA.x += __shfl_xor(sA.x, 16, 64); sA.y += __shfl_xor(sA.y, 16, 64);
    sB.x += __shfl_xor(sB.x, 16, 64); sB.y += __shfl_xor(sB.y, 16, 64);
    sC.x += __shfl_xor(sC.x, 16, 64); sC.y += __shfl_xor(sC.y, 16, 64);
    sD.x += __shfl_xor(sD.x, 16, 64); sD.y += __shfl_xor(sD.y, 16, 64);
    sA.x += __shfl_xor(sA.x, 32, 64); sA.y += __shfl_xor(sA.y, 32, 64);
    sB.x += __shfl_xor(sB.x, 32, 64); sB.y += __shfl_xor(sB.y, 32, 64);
    sC.x += __shfl_xor(sC.x, 32, 64); sC.y += __shfl_xor(sC.y, 32, 64);
    sD.x += __shfl_xor(sD.x, 32, 64); sD.y += __shfl_xor(sD.y, 32, 64);

    if (eg == 0) {
        const float k15 = 1.f / 32768.f;   // fold fix15 weight scale here (exact pow2)
        uint4 h;
        h.x = bf16pair(sA.x * k15, sA.y * k15);
        h.y = bf16pair(sB.x * k15, sB.y * k15);
        h.z = bf16pair(sC.x * k15, sC.y * k15);
        h.w = bf16pair(sD.x * k15, sD.y * k15);
        B16[(((long long)node) << 3) + (lane & 7)] = h;
    }
}

// dot: half-wave (32 lanes) per batch element; lane covers 2 dims (one uint).
// gamma = dot( sum_l U_l , sum_l I_l ) / 16, layers read from E0,B1,B2,B3.
__global__ void dot_kernel(const unsigned* __restrict__ E0,
                           const unsigned* __restrict__ B1,
                           const unsigned* __restrict__ B2,
                           const unsigned* __restrict__ B3,
                           const int* __restrict__ users,
                           const int* __restrict__ items,
                           float* __restrict__ out) {
    int t = blockIdx.x * blockDim.x + threadIdx.x;
    int b = t >> 5;
    int lane = t & 31;
    if (b >= BATCH) return;
    long long uo = ((long long)users[b] << 5) + lane;
    long long io = ((long long)(items[b] + NUM_USERS) << 5) + lane;
    unsigned a0 = E0[uo], a1 = B1[uo], a2 = B2[uo], a3 = B3[uo];
    unsigned c0 = E0[io], c1 = B1[io], c2 = B2[io], c3 = B3[io];
    float ux = (blo(a0) + blo(a1)) + (blo(a2) + blo(a3));
    float uy = (bhi(a0) + bhi(a1)) + (bhi(a2) + bhi(a3));
    float ix = (blo(c0) + blo(c1)) + (blo(c2) + blo(c3));
    float iy = (bhi(c0) + bhi(c1)) + (bhi(c2) + bhi(c3));
    float p = ux * ix + uy * iy;
    #pragma unroll
    for (int off = 16; off >= 1; off >>= 1)
        p += __shfl_xor(p, off, 64);   // stays within the aligned 32-group
    if (lane == 0) out[b] = p * 0.0625f;
}

extern "C" void kernel_launch(void* const* d_in, const int* in_sizes, int n_in,
                              void* d_out, int out_size, void* d_ws, size_t ws_size,
                              hipStream_t stream) {
    const float* user_emb = (const float*)d_in[0];
    const float* item_emb = (const float*)d_in[1];
    const float* edge_val = (const float*)d_in[2];
    const int*   edge_src = (const int*)d_in[3];
    const int*   edge_dst = (const int*)d_in[4];
    const int*   users    = (const int*)d_in[5];
    const int*   items    = (const int*)d_in[6];
    float* out = (float*)d_out;

    const size_t emb16Bytes = (size_t)N_NODES * EMB_DIM * 2;               // 12.8 MB
    const size_t sortBytes  = (size_t)NBUCK_USED * CAP * sizeof(unsigned); // 14.4 MB
    const size_t tmpBytes   = (size_t)NBUCK_USED * CAP * sizeof(ull);      // 28.8 MB
    const size_t nodeBytes  = (size_t)N_NODES * sizeof(int);               // 400 KB

    char* w = (char*)d_ws;
    unsigned* E0           = (unsigned*)(w); w += emb16Bytes;
    unsigned* B1           = (unsigned*)(w); w += emb16Bytes;
    unsigned* B2           = (unsigned*)(w); w += emb16Bytes;
    unsigned* B3           = (unsigned*)(w); w += emb16Bytes;
    unsigned* sorted       = (unsigned*)(w); w += sortBytes;
    ull*      tmp          = (ull*)(w);      w += tmpBytes;
    int*      deg          = (int*)(w);      w += nodeBytes;
    int*      rowStart     = (int*)(w);      w += nodeBytes;
    int*      bucketCursor = (int*)(w);      w += NBUCK * sizeof(int);
    unsigned char* flags   = (unsigned char*)(w); w += N_NODES;

    const int vecTotal   = N_NODES * (EMB_DIM / 4);
    const int initBlocks = (vecTotal + 255) / 256;
    const int tileBlocks = (NNZ + TILE_EDGES - 1) / TILE_EDGES;   // 391

    init_emb_kernel<<<initBlocks, 256, 0, stream>>>(user_emb, item_emb, E0,
                                                    bucketCursor, flags, users, items);

    partA_kernel<<<tileBlocks, 1024, 0, stream>>>(edge_val, edge_src, edge_dst,
                                                  bucketCursor, tmp);
    partB_kernel<<<NBUCK_USED, 1024, 0, stream>>>(tmp, bucketCursor,
                                                  rowStart, deg, sorted);

    const int pullBlocks = (N_NODES * 64 + 255) / 256;
    pull_kernel<<<pullBlocks, 256, 0, stream>>>((const unsigned char*)E0, (uint4*)B1,
                                                sorted, rowStart, deg, flags, 0);
    pull_kernel<<<pullBlocks, 256, 0, stream>>>((const unsigned char*)B1, (uint4*)B2,
                                                sorted, rowStart, deg, flags, 0);
    pull_kernel<<<pullBlocks, 256, 0, stream>>>((const unsigned char*)B2, (uint4*)B3,
                                                sorted, rowStart, deg, flags, 1);

    const int dotBlocks = (BATCH * 32 + 255) / 256;
    dot_kernel<<<dotBlocks, 256, 0, stream>>>(E0, B1, B2, B3, users, items, out);
}